// Round 1
// baseline (482.147 us; speedup 1.0000x reference)
//
#include <hip/hip_runtime.h>

typedef unsigned short u16;
typedef unsigned int u32;
typedef __attribute__((ext_vector_type(4))) float f32x4;
typedef __attribute__((ext_vector_type(8))) short bf16x8;
typedef __attribute__((ext_vector_type(4))) u16 u16x4;
typedef __attribute__((ext_vector_type(8))) u16 u16x8;

#define B_ 16
#define N_ 1024
#define D_ 1024

__device__ __forceinline__ float bf2f(u16 v) {
  return __uint_as_float((u32)v << 16);
}
__device__ __forceinline__ u16 f2bf(float f) {
  u32 u = __float_as_uint(f);
  return (u16)((u + 0x7FFFu + ((u >> 16) & 1u)) >> 16);
}
__device__ __forceinline__ void gload_lds16(const void* g, void* l) {
  __builtin_amdgcn_global_load_lds(
      (const __attribute__((address_space(1))) void*)g,
      (__attribute__((address_space(3))) void*)l, 16, 0, 0);
}

// ---------------- cast fp32 -> bf16 (vectorized) ----------------
__global__ __launch_bounds__(256) void cast_kernel(const float* __restrict__ in,
                                                   u16* __restrict__ out, int n4) {
  const int stride = gridDim.x * blockDim.x;
  for (int i = blockIdx.x * blockDim.x + threadIdx.x; i < n4; i += stride) {
    float4 v = ((const float4*)in)[i];
    u16x4 o;
    o[0] = f2bf(v.x); o[1] = f2bf(v.y); o[2] = f2bf(v.z); o[3] = f2bf(v.w);
    ((u16x4*)out)[i] = o;
  }
}

// ---------------- bt-form GEMM: C[i,j] = sum_k A[i,k]*B[j,k] ----------------
// 128x128 tile, BK=32, 4 waves (2x2), each wave 64x64 (4x4 frags of 16x16x32).
template <typename OutT>
__global__ __launch_bounds__(256) void gemm_bt(
    const u16* __restrict__ A, const u16* __restrict__ Bm, OutT* __restrict__ C,
    int K, int ldc, long long sA, long long sB, long long sC) {
  __shared__ u16 As[128 * 32];
  __shared__ u16 Bs[128 * 32];
  const int tid = threadIdx.x;
  const int lane = tid & 63;
  const int wave = tid >> 6;
  const int wr = wave >> 1, wc = wave & 1;
  A += (long long)blockIdx.z * sA;
  Bm += (long long)blockIdx.z * sB;
  C += (long long)blockIdx.z * sC;
  const int row0 = blockIdx.y * 128, col0 = blockIdx.x * 128;

  f32x4 acc[4][4] = {};
  const int rl = lane & 15, kl = lane >> 4;

  for (int k0 = 0; k0 < K; k0 += 32) {
#pragma unroll
    for (int i = 0; i < 2; ++i) {
      const int e = i * 2048 + tid * 8;   // element offset in 128x32 tile
      const int r = e >> 5, c = e & 31;
      gload_lds16(A + (size_t)(row0 + r) * K + (k0 + c), &As[e]);
      gload_lds16(Bm + (size_t)(col0 + r) * K + (k0 + c), &Bs[e]);
    }
    __syncthreads();
    bf16x8 af[4], bfr[4];
#pragma unroll
    for (int mi = 0; mi < 4; ++mi)
      af[mi] = *(const bf16x8*)&As[(wr * 64 + mi * 16 + rl) * 32 + kl * 8];
#pragma unroll
    for (int ni = 0; ni < 4; ++ni)
      bfr[ni] = *(const bf16x8*)&Bs[(wc * 64 + ni * 16 + rl) * 32 + kl * 8];
#pragma unroll
    for (int mi = 0; mi < 4; ++mi)
#pragma unroll
      for (int ni = 0; ni < 4; ++ni)
        acc[mi][ni] = __builtin_amdgcn_mfma_f32_16x16x32_bf16(
            af[mi], bfr[ni], acc[mi][ni], 0, 0, 0);
    __syncthreads();
  }
#pragma unroll
  for (int mi = 0; mi < 4; ++mi)
#pragma unroll
    for (int ni = 0; ni < 4; ++ni)
#pragma unroll
      for (int j = 0; j < 4; ++j) {
        const int rr = row0 + wr * 64 + mi * 16 + (lane >> 4) * 4 + j;
        const int cc = col0 + wc * 64 + ni * 16 + rl;
        const float v = acc[mi][ni][j];
        if constexpr (sizeof(OutT) == 2)
          C[(size_t)rr * ldc + cc] = (OutT)f2bf(v);
        else
          C[(size_t)rr * ldc + cc] = v;
      }
}

// ---------------- key: softmax over d (rows), write transposed KT[b,d,n] ----------------
__global__ __launch_bounds__(256) void key_sm_t(const u16* __restrict__ Kp,
                                                u16* __restrict__ KT) {
  const int b = blockIdx.y, n0 = blockIdx.x * 64;
  const int tid = threadIdx.x, lane = tid & 63, w = tid >> 6;
  __shared__ float smax[64], sinv[64];
  __shared__ u16 Tl[64][72];
  const u16* base = Kp + ((size_t)b * N_ + n0) * D_;
  // phase 1: per-row max & sum (wave w owns rows w*16 .. w*16+15)
  for (int i = 0; i < 16; ++i) {
    const int r = w * 16 + i;
    const u16x8* rp = (const u16x8*)(base + (size_t)r * D_ + lane * 16);
    u16x8 v0 = rp[0], v1 = rp[1];
    float f[16];
#pragma unroll
    for (int j = 0; j < 8; ++j) { f[j] = bf2f(v0[j]); f[8 + j] = bf2f(v1[j]); }
    float m = -1e30f;
#pragma unroll
    for (int j = 0; j < 16; ++j) m = fmaxf(m, f[j]);
    for (int off = 32; off; off >>= 1) m = fmaxf(m, __shfl_xor(m, off));
    float s = 0.f;
#pragma unroll
    for (int j = 0; j < 16; ++j) s += __expf(f[j] - m);
    for (int off = 32; off; off >>= 1) s += __shfl_xor(s, off);
    if (lane == 0) { smax[r] = m; sinv[r] = 1.f / s; }
  }
  __syncthreads();
  // phase 2: normalize + transpose 64x64 tiles
  for (int ct = 0; ct < 16; ++ct) {
    const int r = tid >> 2, cb = (tid & 3) * 16;
    const u16x8* rp = (const u16x8*)(base + (size_t)r * D_ + ct * 64 + cb);
    u16x8 v0 = rp[0], v1 = rp[1];
    const float m = smax[r], inv = sinv[r];
#pragma unroll
    for (int j = 0; j < 8; ++j) {
      Tl[r][cb + j] = f2bf(__expf(bf2f(v0[j]) - m) * inv);
      Tl[r][cb + 8 + j] = f2bf(__expf(bf2f(v1[j]) - m) * inv);
    }
    __syncthreads();
    const int c = tid >> 2, nb = (tid & 3) * 16;
    u16x8 o0, o1;
#pragma unroll
    for (int e = 0; e < 8; ++e) { o0[e] = Tl[nb + e][c]; o1[e] = Tl[nb + 8 + e][c]; }
    u16x8* op = (u16x8*)(KT + ((size_t)b * D_ + ct * 64 + c) * N_ + n0 + nb);
    op[0] = o0; op[1] = o1;
    __syncthreads();
  }
}

// ---------------- query: softmax over n (cols), write transposed QT[b,d,n] ----------------
__global__ __launch_bounds__(256) void query_sm_t(const u16* __restrict__ Qp,
                                                  u16* __restrict__ QT) {
  const int b = blockIdx.y, d0 = blockIdx.x * 64;
  const int tid = threadIdx.x, l = tid & 63, g = tid >> 6;
  __shared__ float pm[4][64], ps[4][64];
  __shared__ float cmax[64], cinv[64];
  __shared__ u16 Tl[64][72];
  const u16* base = Qp + (size_t)b * N_ * D_;
  // phase 1: online max/sum over n, 4 n-segments in parallel
  float m = -1e30f, s = 0.f;
  for (int n = g * 256; n < g * 256 + 256; ++n) {
    const float x = bf2f(base[(size_t)n * D_ + d0 + l]);
    const float nm = fmaxf(m, x);
    s = s * __expf(m - nm) + __expf(x - nm);
    m = nm;
  }
  pm[g][l] = m; ps[g][l] = s;
  __syncthreads();
  if (tid < 64) {
    float M = pm[0][tid];
    for (int k2 = 1; k2 < 4; ++k2) M = fmaxf(M, pm[k2][tid]);
    float S = 0.f;
    for (int k2 = 0; k2 < 4; ++k2) S += ps[k2][tid] * __expf(pm[k2][tid] - M);
    cmax[tid] = M; cinv[tid] = 1.f / S;
  }
  __syncthreads();
  // phase 2: normalize + transpose
  for (int nt = 0; nt < 16; ++nt) {
    const int r = tid >> 2, cb = (tid & 3) * 16;
    const u16x8* rp = (const u16x8*)(base + (size_t)(nt * 64 + r) * D_ + d0 + cb);
    u16x8 v0 = rp[0], v1 = rp[1];
#pragma unroll
    for (int j = 0; j < 8; ++j) {
      Tl[r][cb + j] = f2bf(__expf(bf2f(v0[j]) - cmax[cb + j]) * cinv[cb + j]);
      Tl[r][cb + 8 + j] =
          f2bf(__expf(bf2f(v1[j]) - cmax[cb + 8 + j]) * cinv[cb + 8 + j]);
    }
    __syncthreads();
    const int c = tid >> 2, nb = (tid & 3) * 16;
    u16x8 o0, o1;
#pragma unroll
    for (int e = 0; e < 8; ++e) { o0[e] = Tl[nb + e][c]; o1[e] = Tl[nb + 8 + e][c]; }
    u16x8* op = (u16x8*)(QT + ((size_t)b * D_ + d0 + c) * N_ + nt * 64 + nb);
    op[0] = o0; op[1] = o1;
    __syncthreads();
  }
}

extern "C" void kernel_launch(void* const* d_in, const int* in_sizes, int n_in,
                              void* d_out, int out_size, void* d_ws, size_t ws_size,
                              hipStream_t stream) {
  const float* x = (const float*)d_in[0];
  const float* Wk = (const float*)d_in[1];
  const float* Wq = (const float*)d_in[2];
  const float* Wv = (const float*)d_in[3];
  const float* Wr = (const float*)d_in[4];
  float* out = (float*)d_out;
  char* ws = (char*)d_ws;
  const size_t MB = 1ull << 20;

  // workspace layout (168 MB peak, with reuse)
  u16* Xb  = (u16*)(ws + 0 * MB);    // 32 MB; reused as KT after projections
  u16* KT  = (u16*)(ws + 0 * MB);
  u16* Wkb = (u16*)(ws + 32 * MB);   // 2 MB each
  u16* Wqb = (u16*)(ws + 34 * MB);
  u16* Wvb = (u16*)(ws + 36 * MB);
  u16* Wrb = (u16*)(ws + 38 * MB);
  u16* Kp  = (u16*)(ws + 40 * MB);   // 32 MB; reused as St
  u16* St  = (u16*)(ws + 40 * MB);
  u16* Qp  = (u16*)(ws + 72 * MB);   // 32 MB; reused as attended
  u16* Att = (u16*)(ws + 72 * MB);
  u16* V   = (u16*)(ws + 104 * MB);  // 32 MB
  u16* QT  = (u16*)(ws + 136 * MB);  // 32 MB

  const int nX = B_ * N_ * D_;
  cast_kernel<<<2048, 256, 0, stream>>>(x, Xb, nX / 4);
  cast_kernel<<<512, 256, 0, stream>>>(Wk, Wkb, (D_ * D_) / 4);
  cast_kernel<<<512, 256, 0, stream>>>(Wq, Wqb, (D_ * D_) / 4);
  cast_kernel<<<512, 256, 0, stream>>>(Wv, Wvb, (D_ * D_) / 4);
  cast_kernel<<<512, 256, 0, stream>>>(Wr, Wrb, (D_ * D_) / 4);

  // projections: C (B*N, D) = Xb (B*N, D) @ W^T   [bt-form]
  const dim3 gproj(D_ / 128, (B_ * N_) / 128, 1);
  gemm_bt<u16><<<gproj, 256, 0, stream>>>(Xb, Wkb, Kp, D_, D_, 0, 0, 0);
  gemm_bt<u16><<<gproj, 256, 0, stream>>>(Xb, Wqb, Qp, D_, D_, 0, 0, 0);
  gemm_bt<u16><<<gproj, 256, 0, stream>>>(Xb, Wvb, V, D_, D_, 0, 0, 0);

  // softmaxes + transposes (KT overwrites Xb; projections are complete)
  key_sm_t<<<dim3(N_ / 64, B_), 256, 0, stream>>>(Kp, KT);
  query_sm_t<<<dim3(D_ / 64, B_), 256, 0, stream>>>(Qp, QT);

  const long long sNN = (long long)N_ * D_;
  // St[b,d',d] = sum_n QT[b,d',n] * KT[b,d,n]   (St overwrites Kp)
  gemm_bt<u16><<<dim3(D_ / 128, D_ / 128, B_), 256, 0, stream>>>(
      QT, KT, St, N_, D_, sNN, sNN, sNN);
  // Att[b,m,d'] = sum_d V[b,m,d] * St[b,d',d]   (Att overwrites Qp)
  gemm_bt<u16><<<dim3(D_ / 128, N_ / 128, B_), 256, 0, stream>>>(
      V, St, Att, D_, D_, sNN, sNN, sNN);
  // out = Att @ Wr^T  (fp32 epilogue)
  gemm_bt<float><<<dim3(D_ / 128, (B_ * N_) / 128, 1), 256, 0, stream>>>(
      Att, Wrb, out, D_, D_, 0, 0, 0);
}

// Round 3
// 330.527 us; speedup vs baseline: 1.4587x; 1.4587x over previous
//
#include <hip/hip_runtime.h>

typedef unsigned short u16;
typedef unsigned int u32;
typedef __attribute__((ext_vector_type(4))) float f32x4;
typedef __attribute__((ext_vector_type(8))) short bf16x8;
typedef __attribute__((ext_vector_type(4))) u16 u16x4;
typedef __attribute__((ext_vector_type(8))) u16 u16x8;

#define B_ 16
#define N_ 1024
#define D_ 1024
#define BM 256
#define BN 256
#define BK 64
#define TILE_BYTES (BM * BK * 2)  // 32 KiB per (buf, A/B) tile

__device__ __forceinline__ float bf2f(u16 v) {
  return __uint_as_float((u32)v << 16);
}
__device__ __forceinline__ u16 f2bf(float f) {
  u32 u = __float_as_uint(f);
  return (u16)((u + 0x7FFFu + ((u >> 16) & 1u)) >> 16);
}
__device__ __forceinline__ void gload_lds16(const void* g, void* l) {
  __builtin_amdgcn_global_load_lds(
      (const __attribute__((address_space(1))) void*)g,
      (__attribute__((address_space(3))) void*)l, 16, 0, 0);
}

// ---------------- cast fp32 -> bf16 (vectorized) ----------------
__global__ __launch_bounds__(256) void cast_kernel(const float* __restrict__ in,
                                                   u16* __restrict__ out, int n4) {
  const int stride = gridDim.x * blockDim.x;
  for (int i = blockIdx.x * blockDim.x + threadIdx.x; i < n4; i += stride) {
    float4 v = ((const float4*)in)[i];
    u16x4 o;
    o[0] = f2bf(v.x); o[1] = f2bf(v.y); o[2] = f2bf(v.z); o[3] = f2bf(v.w);
    ((u16x4*)out)[i] = o;
  }
}

// ---------------- 256x256 8-wave 4-phase bt-GEMM ----------------
// C[i,j] = sum_k A[i,k]*B[j,k].  Grid MUST be exactly 256 blocks (1/CU).
// LDS: 2 buffers x (A 256x64 + B 256x64) bf16 = 128 KiB, XOR-swizzled
// byte^=((row&7)<<4), applied to pre-swizzled global source + ds_read addr.
template <typename OutT>
__global__ __launch_bounds__(512, 2) void gemm_bt256(
    const u16* __restrict__ A, const u16* __restrict__ Bm, OutT* __restrict__ C,
    int K, int ldc, long long sA, long long sB, long long sC,
    int tx_n, int nb_per) {
  __shared__ u16 lds[2][2][BM * BK];  // [buf][0=A,1=B]
  const int tid = threadIdx.x;
  const int lane = tid & 63;
  const int wid = tid >> 6;
  const int wm = wid >> 2;   // 0..1 -> 128 rows
  const int wn = wid & 3;    // 0..3 -> 64 cols
  const int rl = lane & 15, kl = lane >> 4;

  // bijective XCD swizzle over 256 blocks (8 XCDs x 32-chunk)
  const int orig = blockIdx.x;
  const int wgid = ((orig & 7) << 5) | (orig >> 3);
  const int batch = wgid / nb_per;
  const int rem = wgid % nb_per;
  const int row0 = (rem / tx_n) * BM, col0 = (rem % tx_n) * BN;
  A += (long long)batch * sA;
  Bm += (long long)batch * sB;
  C += (long long)batch * sC;

  // LDS tile base addresses via offset arithmetic (no pointer-array init —
  // braced arrays of LDS-cast pointers fail gfx950 codegen).
  auto ldsTile = [&](int buf, int ab) -> char* {
    return (char*)&lds[0][0][0] + (size_t)(buf * 2 + ab) * TILE_BYTES;
  };

  // stage one 256x64 bf16 tile (32 KB) = 4 gload_lds calls, linear LDS dest,
  // inverse-swizzled global source.
  auto stageA = [&](int t, int buf) {
    char* base = ldsTile(buf, 0);
#pragma unroll
    for (int g = 0; g < 4; ++g) {
      const int d = g * 8192 + tid * 16;
      const int r = d >> 7;
      const int li = (d & 127) ^ ((r & 7) << 4);
      gload_lds16(A + (size_t)(row0 + r) * K + t * BK + (li >> 1), base + d);
    }
  };
  auto stageB = [&](int t, int buf) {
    char* base = ldsTile(buf, 1);
#pragma unroll
    for (int g = 0; g < 4; ++g) {
      const int d = g * 8192 + tid * 16;
      const int r = d >> 7;
      const int li = (d & 127) ^ ((r & 7) << 4);
      gload_lds16(Bm + (size_t)(col0 + r) * K + t * BK + (li >> 1), base + d);
    }
  };
  // swizzled fragment reads (b128)
  auto rdA = [&](int buf, int mi, int kk) -> bf16x8 {
    const int R = wm * 128 + mi * 16 + rl;
    const int p = (R * 128 + kk * 64 + kl * 16) ^ ((R & 7) << 4);
    return *(const bf16x8*)(ldsTile(buf, 0) + p);
  };
  auto rdB = [&](int buf, int ni, int kk) -> bf16x8 {
    const int R = wn * 64 + ni * 16 + rl;
    const int p = (R * 128 + kk * 64 + kl * 16) ^ ((R & 7) << 4);
    return *(const bf16x8*)(ldsTile(buf, 1) + p);
  };

  f32x4 acc[8][4] = {};
  bf16x8 aF[4][2], bLo[2][2], bHi[2][2];

  // prologue: tiles 0,1
  stageB(0, 0); stageA(0, 0);
  stageB(1, 1); stageA(1, 1);
  asm volatile("s_waitcnt vmcnt(8)" ::: "memory");
  __builtin_amdgcn_s_barrier();

  const int nt = K / BK;
  for (int t = 0; t < nt; ++t) {
    const int cur = t & 1;
    const bool pf = (t + 2) < nt;
    // ---- P1: A-lo + B-lo reads, MFMA Q(lo,lo) ----
#pragma unroll
    for (int mi = 0; mi < 4; ++mi) {
      aF[mi][0] = rdA(cur, mi, 0); aF[mi][1] = rdA(cur, mi, 1);
    }
#pragma unroll
    for (int ni = 0; ni < 2; ++ni) {
      bLo[ni][0] = rdB(cur, ni, 0); bLo[ni][1] = rdB(cur, ni, 1);
    }
    asm volatile("" ::: "memory");
    __builtin_amdgcn_s_barrier();
    asm volatile("s_waitcnt lgkmcnt(0)" ::: "memory");
    __builtin_amdgcn_s_setprio(1);
#pragma unroll
    for (int kk = 0; kk < 2; ++kk)
#pragma unroll
      for (int mi = 0; mi < 4; ++mi)
#pragma unroll
        for (int ni = 0; ni < 2; ++ni)
          acc[mi][ni] = __builtin_amdgcn_mfma_f32_16x16x32_bf16(
              aF[mi][kk], bLo[ni][kk], acc[mi][ni], 0, 0, 0);
    __builtin_amdgcn_s_setprio(0);
    asm volatile("" ::: "memory");
    __builtin_amdgcn_s_barrier();
    // ---- P2: B-hi reads, MFMA Q(lo,hi) ----
#pragma unroll
    for (int ni = 0; ni < 2; ++ni) {
      bHi[ni][0] = rdB(cur, 2 + ni, 0); bHi[ni][1] = rdB(cur, 2 + ni, 1);
    }
    asm volatile("" ::: "memory");
    __builtin_amdgcn_s_barrier();
    asm volatile("s_waitcnt lgkmcnt(0)" ::: "memory");
    __builtin_amdgcn_s_setprio(1);
#pragma unroll
    for (int kk = 0; kk < 2; ++kk)
#pragma unroll
      for (int mi = 0; mi < 4; ++mi)
#pragma unroll
        for (int ni = 0; ni < 2; ++ni)
          acc[mi][2 + ni] = __builtin_amdgcn_mfma_f32_16x16x32_bf16(
              aF[mi][kk], bHi[ni][kk], acc[mi][2 + ni], 0, 0, 0);
    __builtin_amdgcn_s_setprio(0);
    asm volatile("" ::: "memory");
    __builtin_amdgcn_s_barrier();
    // ---- P3: A-hi reads + stage B(t+2) into cur (B free after P2), Q(hi,hi) ----
#pragma unroll
    for (int mi = 0; mi < 4; ++mi) {
      aF[mi][0] = rdA(cur, 4 + mi, 0); aF[mi][1] = rdA(cur, 4 + mi, 1);
    }
    if (pf) stageB(t + 2, cur);
    asm volatile("" ::: "memory");
    __builtin_amdgcn_s_barrier();
    asm volatile("s_waitcnt lgkmcnt(0)" ::: "memory");
    __builtin_amdgcn_s_setprio(1);
#pragma unroll
    for (int kk = 0; kk < 2; ++kk)
#pragma unroll
      for (int mi = 0; mi < 4; ++mi)
#pragma unroll
        for (int ni = 0; ni < 2; ++ni)
          acc[4 + mi][2 + ni] = __builtin_amdgcn_mfma_f32_16x16x32_bf16(
              aF[mi][kk], bHi[ni][kk], acc[4 + mi][2 + ni], 0, 0, 0);
    __builtin_amdgcn_s_setprio(0);
    asm volatile("" ::: "memory");
    __builtin_amdgcn_s_barrier();
    // ---- P4: stage A(t+2) into cur (A free after P3), Q(hi,lo), vmcnt gate ----
    if (pf) stageA(t + 2, cur);
    asm volatile("" ::: "memory");
    __builtin_amdgcn_s_barrier();
    __builtin_amdgcn_s_setprio(1);
#pragma unroll
    for (int kk = 0; kk < 2; ++kk)
#pragma unroll
      for (int mi = 0; mi < 4; ++mi)
#pragma unroll
        for (int ni = 0; ni < 2; ++ni)
          acc[4 + mi][ni] = __builtin_amdgcn_mfma_f32_16x16x32_bf16(
              aF[mi][kk], bLo[ni][kk], acc[4 + mi][ni], 0, 0, 0);
    __builtin_amdgcn_s_setprio(0);
    if (pf) asm volatile("s_waitcnt vmcnt(8)" ::: "memory");
    else    asm volatile("s_waitcnt vmcnt(0)" ::: "memory");
    asm volatile("" ::: "memory");
    __builtin_amdgcn_s_barrier();
  }
  // epilogue: C/D map col=lane&15, row=(lane>>4)*4+j
#pragma unroll
  for (int mi = 0; mi < 8; ++mi)
#pragma unroll
    for (int ni = 0; ni < 4; ++ni)
#pragma unroll
      for (int j = 0; j < 4; ++j) {
        const int rr = row0 + wm * 128 + mi * 16 + kl * 4 + j;
        const int cc = col0 + wn * 64 + ni * 16 + rl;
        const float v = acc[mi][ni][j];
        if constexpr (sizeof(OutT) == 2)
          C[(size_t)rr * ldc + cc] = (OutT)f2bf(v);
        else
          C[(size_t)rr * ldc + cc] = v;
      }
}

// ---------------- key: softmax over d (rows), write transposed KT[b,d,n] ----------------
__global__ __launch_bounds__(256) void key_sm_t(const u16* __restrict__ Kp,
                                                u16* __restrict__ KT) {
  const int b = blockIdx.y, n0 = blockIdx.x * 64;
  const int tid = threadIdx.x, lane = tid & 63, w = tid >> 6;
  __shared__ float smax[64], sinv[64];
  __shared__ u16 Tl[64][72];
  const u16* base = Kp + ((size_t)b * N_ + n0) * D_;
  for (int i = 0; i < 16; ++i) {
    const int r = w * 16 + i;
    const u16x8* rp = (const u16x8*)(base + (size_t)r * D_ + lane * 16);
    u16x8 v0 = rp[0], v1 = rp[1];
    float f[16];
#pragma unroll
    for (int j = 0; j < 8; ++j) { f[j] = bf2f(v0[j]); f[8 + j] = bf2f(v1[j]); }
    float m = -1e30f;
#pragma unroll
    for (int j = 0; j < 16; ++j) m = fmaxf(m, f[j]);
    for (int off = 32; off; off >>= 1) m = fmaxf(m, __shfl_xor(m, off));
    float s = 0.f;
#pragma unroll
    for (int j = 0; j < 16; ++j) s += __expf(f[j] - m);
    for (int off = 32; off; off >>= 1) s += __shfl_xor(s, off);
    if (lane == 0) { smax[r] = m; sinv[r] = 1.f / s; }
  }
  __syncthreads();
  for (int ct = 0; ct < 16; ++ct) {
    const int r = tid >> 2, cb = (tid & 3) * 16;
    const u16x8* rp = (const u16x8*)(base + (size_t)r * D_ + ct * 64 + cb);
    u16x8 v0 = rp[0], v1 = rp[1];
    const float m = smax[r], inv = sinv[r];
#pragma unroll
    for (int j = 0; j < 8; ++j) {
      Tl[r][cb + j] = f2bf(__expf(bf2f(v0[j]) - m) * inv);
      Tl[r][cb + 8 + j] = f2bf(__expf(bf2f(v1[j]) - m) * inv);
    }
    __syncthreads();
    const int c = tid >> 2, nb = (tid & 3) * 16;
    u16x8 o0, o1;
#pragma unroll
    for (int e = 0; e < 8; ++e) { o0[e] = Tl[nb + e][c]; o1[e] = Tl[nb + 8 + e][c]; }
    u16x8* op = (u16x8*)(KT + ((size_t)b * D_ + ct * 64 + c) * N_ + n0 + nb);
    op[0] = o0; op[1] = o1;
    __syncthreads();
  }
}

// ---------------- query: softmax over n (cols), write transposed QT[b,d,n] ----------------
__global__ __launch_bounds__(256) void query_sm_t(const u16* __restrict__ Qp,
                                                  u16* __restrict__ QT) {
  const int b = blockIdx.y, d0 = blockIdx.x * 64;
  const int tid = threadIdx.x, l = tid & 63, g = tid >> 6;
  __shared__ float pm[4][64], ps[4][64];
  __shared__ float cmax[64], cinv[64];
  __shared__ u16 Tl[64][72];
  const u16* base = Qp + (size_t)b * N_ * D_;
  float m = -1e30f, s = 0.f;
  for (int n = g * 256; n < g * 256 + 256; ++n) {
    const float x = bf2f(base[(size_t)n * D_ + d0 + l]);
    const float nm = fmaxf(m, x);
    s = s * __expf(m - nm) + __expf(x - nm);
    m = nm;
  }
  pm[g][l] = m; ps[g][l] = s;
  __syncthreads();
  if (tid < 64) {
    float M = pm[0][tid];
    for (int k2 = 1; k2 < 4; ++k2) M = fmaxf(M, pm[k2][tid]);
    float S = 0.f;
    for (int k2 = 0; k2 < 4; ++k2) S += ps[k2][tid] * __expf(pm[k2][tid] - M);
    cmax[tid] = M; cinv[tid] = 1.f / S;
  }
  __syncthreads();
  for (int nt = 0; nt < 16; ++nt) {
    const int r = tid >> 2, cb = (tid & 3) * 16;
    const u16x8* rp = (const u16x8*)(base + (size_t)(nt * 64 + r) * D_ + d0 + cb);
    u16x8 v0 = rp[0], v1 = rp[1];
#pragma unroll
    for (int j = 0; j < 8; ++j) {
      Tl[r][cb + j] = f2bf(__expf(bf2f(v0[j]) - cmax[cb + j]) * cinv[cb + j]);
      Tl[r][cb + 8 + j] =
          f2bf(__expf(bf2f(v1[j]) - cmax[cb + 8 + j]) * cinv[cb + 8 + j]);
    }
    __syncthreads();
    const int c = tid >> 2, nb = (tid & 3) * 16;
    u16x8 o0, o1;
#pragma unroll
    for (int e = 0; e < 8; ++e) { o0[e] = Tl[nb + e][c]; o1[e] = Tl[nb + 8 + e][c]; }
    u16x8* op = (u16x8*)(QT + ((size_t)b * D_ + d0 + c) * N_ + nt * 64 + nb);
    op[0] = o0; op[1] = o1;
    __syncthreads();
  }
}

extern "C" void kernel_launch(void* const* d_in, const int* in_sizes, int n_in,
                              void* d_out, int out_size, void* d_ws, size_t ws_size,
                              hipStream_t stream) {
  const float* x = (const float*)d_in[0];
  const float* Wk = (const float*)d_in[1];
  const float* Wq = (const float*)d_in[2];
  const float* Wv = (const float*)d_in[3];
  const float* Wr = (const float*)d_in[4];
  float* out = (float*)d_out;
  char* ws = (char*)d_ws;
  const size_t MB = 1ull << 20;

  u16* Xb  = (u16*)(ws + 0 * MB);
  u16* KT  = (u16*)(ws + 0 * MB);
  u16* Wkb = (u16*)(ws + 32 * MB);
  u16* Wqb = (u16*)(ws + 34 * MB);
  u16* Wvb = (u16*)(ws + 36 * MB);
  u16* Wrb = (u16*)(ws + 38 * MB);
  u16* Kp  = (u16*)(ws + 40 * MB);
  u16* St  = (u16*)(ws + 40 * MB);
  u16* Qp  = (u16*)(ws + 72 * MB);
  u16* Att = (u16*)(ws + 72 * MB);
  u16* V   = (u16*)(ws + 104 * MB);
  u16* QT  = (u16*)(ws + 136 * MB);

  const int nX = B_ * N_ * D_;
  cast_kernel<<<2048, 256, 0, stream>>>(x, Xb, nX / 4);
  cast_kernel<<<512, 256, 0, stream>>>(Wk, Wkb, (D_ * D_) / 4);
  cast_kernel<<<512, 256, 0, stream>>>(Wq, Wqb, (D_ * D_) / 4);
  cast_kernel<<<512, 256, 0, stream>>>(Wv, Wvb, (D_ * D_) / 4);
  cast_kernel<<<512, 256, 0, stream>>>(Wr, Wrb, (D_ * D_) / 4);

  // projections: (16384 x 1024) = Xb @ W^T   -> 64x4 tiles = 256 blocks
  gemm_bt256<u16><<<256, 512, 0, stream>>>(Xb, Wkb, Kp, D_, D_, 0, 0, 0, 4, 256);
  gemm_bt256<u16><<<256, 512, 0, stream>>>(Xb, Wqb, Qp, D_, D_, 0, 0, 0, 4, 256);
  gemm_bt256<u16><<<256, 512, 0, stream>>>(Xb, Wvb, V, D_, D_, 0, 0, 0, 4, 256);

  key_sm_t<<<dim3(N_ / 64, B_), 256, 0, stream>>>(Kp, KT);
  query_sm_t<<<dim3(D_ / 64, B_), 256, 0, stream>>>(Qp, QT);

  const long long sNN = (long long)N_ * D_;
  // St[b,d',d] = sum_n QT[b,d',n]*KT[b,d,n]: 16 batches x (4x4) = 256 blocks
  gemm_bt256<u16><<<256, 512, 0, stream>>>(QT, KT, St, N_, D_, sNN, sNN, sNN, 4, 16);
  // Att[b,m,d'] = sum_d V[b,m,d]*St[b,d',d]
  gemm_bt256<u16><<<256, 512, 0, stream>>>(V, St, Att, D_, D_, sNN, sNN, sNN, 4, 16);
  // out = Att @ Wr^T (fp32 epilogue)
  gemm_bt256<float><<<256, 512, 0, stream>>>(Att, Wrb, out, D_, D_, 0, 0, 0, 4, 256);
}

// Round 4
// 309.180 us; speedup vs baseline: 1.5594x; 1.0690x over previous
//
#include <hip/hip_runtime.h>

typedef unsigned short u16;
typedef unsigned int u32;
typedef __attribute__((ext_vector_type(4))) float f32x4;
typedef __attribute__((ext_vector_type(8))) short bf16x8;
typedef __attribute__((ext_vector_type(4))) u16 u16x4;
typedef __attribute__((ext_vector_type(8))) u16 u16x8;

#define B_ 16
#define N_ 1024
#define D_ 1024
#define BM 256
#define BN 256
#define BK 64
#define TILE_BYTES (BM * BK * 2)  // 32 KiB per (buf, A/B) tile

__device__ __forceinline__ float bf2f(u16 v) {
  return __uint_as_float((u32)v << 16);
}
__device__ __forceinline__ u16 f2bf(float f) {
  u32 u = __float_as_uint(f);
  return (u16)((u + 0x7FFFu + ((u >> 16) & 1u)) >> 16);
}
__device__ __forceinline__ void gload_lds16(const void* g, void* l) {
  __builtin_amdgcn_global_load_lds(
      (const __attribute__((address_space(1))) void*)g,
      (__attribute__((address_space(3))) void*)l, 16, 0, 0);
}

// ---------------- cast fp32 -> bf16 (vectorized) ----------------
__global__ __launch_bounds__(256) void cast_kernel(const float* __restrict__ in,
                                                   u16* __restrict__ out, int n4) {
  const int stride = gridDim.x * blockDim.x;
  for (int i = blockIdx.x * blockDim.x + threadIdx.x; i < n4; i += stride) {
    float4 v = ((const float4*)in)[i];
    u16x4 o;
    o[0] = f2bf(v.x); o[1] = f2bf(v.y); o[2] = f2bf(v.z); o[3] = f2bf(v.w);
    ((u16x4*)out)[i] = o;
  }
}

// fused cast of the 4 weight matrices into one contiguous bf16 region
__global__ __launch_bounds__(256) void cast4_kernel(
    const float* __restrict__ w0, const float* __restrict__ w1,
    const float* __restrict__ w2, const float* __restrict__ w3,
    u16* __restrict__ out) {
  const int per = (D_ * D_) / 4;
  const int stride = gridDim.x * blockDim.x;
  for (int i = blockIdx.x * blockDim.x + threadIdx.x; i < 4 * per; i += stride) {
    const int w = i / per, r = i - w * per;
    const float* src = (w == 0) ? w0 : (w == 1) ? w1 : (w == 2) ? w2 : w3;
    float4 v = ((const float4*)src)[r];
    u16x4 o;
    o[0] = f2bf(v.x); o[1] = f2bf(v.y); o[2] = f2bf(v.z); o[3] = f2bf(v.w);
    ((u16x4*)out)[i] = o;
  }
}

// ---------------- 256x256 8-wave 2-window bt-GEMM ----------------
// C[i,j] = sum_k A[i,k]*B[j,k].  Grid MUST be exactly 256 blocks (1/CU).
// LDS: 2 buffers x (A 256x64 + B 256x64) bf16 = 128 KiB, XOR-swizzled
// byte^=((row&7)<<4) on pre-swizzled global source + ds_read addr.
// Per K-tile: W1 {A-lo+B reads interleaved w/ 32 MFMA} | b1 | stageB |
//             W2 {A-hi reads + 32 MFMA} | vmcnt(4) | b2 | stageA.
template <typename OutT>
__global__ __launch_bounds__(512, 2) void gemm_bt256(
    const u16* __restrict__ A, const u16* __restrict__ Bm, OutT* __restrict__ C,
    int K, int ldc, long long sA, long long sB, long long sC,
    int tx_n, int nb_per) {
  __shared__ u16 lds[2][2][BM * BK];  // [buf][0=A,1=B]
  const int tid = threadIdx.x;
  const int lane = tid & 63;
  const int wid = tid >> 6;
  const int wm = wid >> 2;   // 0..1 -> 128 rows
  const int wn = wid & 3;    // 0..3 -> 64 cols
  const int rl = lane & 15, kl = lane >> 4;

  // bijective XCD swizzle over 256 blocks (8 XCDs x 32-chunk)
  const int orig = blockIdx.x;
  const int wgid = ((orig & 7) << 5) | (orig >> 3);
  const int batch = wgid / nb_per;
  const int rem = wgid % nb_per;
  const int row0 = (rem / tx_n) * BM, col0 = (rem % tx_n) * BN;
  A += (long long)batch * sA;
  Bm += (long long)batch * sB;
  C += (long long)batch * sC;

  auto ldsTile = [&](int buf, int ab) -> char* {
    return (char*)&lds[0][0][0] + (size_t)(buf * 2 + ab) * TILE_BYTES;
  };

  auto stageA = [&](int t, int buf) {
    char* base = ldsTile(buf, 0);
#pragma unroll
    for (int g = 0; g < 4; ++g) {
      const int d = g * 8192 + tid * 16;
      const int r = d >> 7;
      const int li = (d & 127) ^ ((r & 7) << 4);
      gload_lds16(A + (size_t)(row0 + r) * K + t * BK + (li >> 1), base + d);
    }
  };
  auto stageB = [&](int t, int buf) {
    char* base = ldsTile(buf, 1);
#pragma unroll
    for (int g = 0; g < 4; ++g) {
      const int d = g * 8192 + tid * 16;
      const int r = d >> 7;
      const int li = (d & 127) ^ ((r & 7) << 4);
      gload_lds16(Bm + (size_t)(col0 + r) * K + t * BK + (li >> 1), base + d);
    }
  };
  auto rdA = [&](int buf, int mi, int kk) -> bf16x8 {
    const int R = wm * 128 + mi * 16 + rl;
    const int p = (R * 128 + kk * 64 + kl * 16) ^ ((R & 7) << 4);
    return *(const bf16x8*)(ldsTile(buf, 0) + p);
  };
  auto rdB = [&](int buf, int ni, int kk) -> bf16x8 {
    const int R = wn * 64 + ni * 16 + rl;
    const int p = (R * 128 + kk * 64 + kl * 16) ^ ((R & 7) << 4);
    return *(const bf16x8*)(ldsTile(buf, 1) + p);
  };

  f32x4 acc[8][4] = {};
  bf16x8 aF[4][2], bF[4][2];

  // prologue: tiles 0,1 (16 loads); gate on tile0 (leave tile1's 8 in flight)
  stageB(0, 0); stageA(0, 0);
  stageB(1, 1); stageA(1, 1);
  asm volatile("s_waitcnt vmcnt(8)" ::: "memory");
  __builtin_amdgcn_s_barrier();

  const int nt = K / BK;
  for (int t = 0; t < nt; ++t) {
    const int cur = t & 1;
    const bool pf = (t + 2) < nt;
    // ---- W1: A-lo + all-B reads, 32 MFMA (compiler interleaves via
    //      per-use lgkmcnt) ----
#pragma unroll
    for (int mi = 0; mi < 4; ++mi) {
      aF[mi][0] = rdA(cur, mi, 0); aF[mi][1] = rdA(cur, mi, 1);
    }
#pragma unroll
    for (int ni = 0; ni < 4; ++ni) {
      bF[ni][0] = rdB(cur, ni, 0); bF[ni][1] = rdB(cur, ni, 1);
    }
#pragma unroll
    for (int kk = 0; kk < 2; ++kk)
#pragma unroll
      for (int mi = 0; mi < 4; ++mi)
#pragma unroll
        for (int ni = 0; ni < 4; ++ni)
          acc[mi][ni] = __builtin_amdgcn_mfma_f32_16x16x32_bf16(
              aF[mi][kk], bF[ni][kk], acc[mi][ni], 0, 0, 0);
    // pin read-consuming MFMAs before the barrier (rule #18 hazard), then
    // release B(cur) for staging.
    __builtin_amdgcn_sched_barrier(0);
    __builtin_amdgcn_s_barrier();
    if (pf) stageB(t + 2, cur);
    // ---- W2: A-hi reads, 32 MFMA ----
#pragma unroll
    for (int mi = 0; mi < 4; ++mi) {
      aF[mi][0] = rdA(cur, 4 + mi, 0); aF[mi][1] = rdA(cur, 4 + mi, 1);
    }
#pragma unroll
    for (int kk = 0; kk < 2; ++kk)
#pragma unroll
      for (int mi = 0; mi < 4; ++mi)
#pragma unroll
        for (int ni = 0; ni < 4; ++ni)
          acc[4 + mi][ni] = __builtin_amdgcn_mfma_f32_16x16x32_bf16(
              aF[mi][kk], bF[ni][kk], acc[4 + mi][ni], 0, 0, 0);
    __builtin_amdgcn_sched_barrier(0);
    // gate: tile t+1 must be landed (loads issued after t+1's stageA:
    // stageB(t+2) only -> 4 outstanding allowed in steady state)
    if (pf) asm volatile("s_waitcnt vmcnt(4)" ::: "memory");
    else    asm volatile("s_waitcnt vmcnt(0)" ::: "memory");
    __builtin_amdgcn_s_barrier();
    if (pf) stageA(t + 2, cur);  // A(cur) fully consumed; next iter reads cur^1
  }
  // epilogue: C/D map col=lane&15, row=(lane>>4)*4+j
#pragma unroll
  for (int mi = 0; mi < 8; ++mi)
#pragma unroll
    for (int ni = 0; ni < 4; ++ni)
#pragma unroll
      for (int j = 0; j < 4; ++j) {
        const int rr = row0 + wm * 128 + mi * 16 + kl * 4 + j;
        const int cc = col0 + wn * 64 + ni * 16 + rl;
        const float v = acc[mi][ni][j];
        if constexpr (sizeof(OutT) == 2)
          C[(size_t)rr * ldc + cc] = (OutT)f2bf(v);
        else
          C[(size_t)rr * ldc + cc] = v;
      }
}

// ---------------- key: softmax over d (rows), write transposed KT[b,d,n] ----------------
__global__ __launch_bounds__(256) void key_sm_t(const u16* __restrict__ Kp,
                                                u16* __restrict__ KT) {
  const int b = blockIdx.y, n0 = blockIdx.x * 64;
  const int tid = threadIdx.x, lane = tid & 63, w = tid >> 6;
  __shared__ float smax[64], sinv[64];
  __shared__ u16 Tl[64][72];
  const u16* base = Kp + ((size_t)b * N_ + n0) * D_;
  for (int i = 0; i < 16; ++i) {
    const int r = w * 16 + i;
    const u16x8* rp = (const u16x8*)(base + (size_t)r * D_ + lane * 16);
    u16x8 v0 = rp[0], v1 = rp[1];
    float f[16];
#pragma unroll
    for (int j = 0; j < 8; ++j) { f[j] = bf2f(v0[j]); f[8 + j] = bf2f(v1[j]); }
    float m = -1e30f;
#pragma unroll
    for (int j = 0; j < 16; ++j) m = fmaxf(m, f[j]);
    for (int off = 32; off; off >>= 1) m = fmaxf(m, __shfl_xor(m, off));
    float s = 0.f;
#pragma unroll
    for (int j = 0; j < 16; ++j) s += __expf(f[j] - m);
    for (int off = 32; off; off >>= 1) s += __shfl_xor(s, off);
    if (lane == 0) { smax[r] = m; sinv[r] = 1.f / s; }
  }
  __syncthreads();
  for (int ct = 0; ct < 16; ++ct) {
    const int r = tid >> 2, cb = (tid & 3) * 16;
    const u16x8* rp = (const u16x8*)(base + (size_t)r * D_ + ct * 64 + cb);
    u16x8 v0 = rp[0], v1 = rp[1];
    const float m = smax[r], inv = sinv[r];
#pragma unroll
    for (int j = 0; j < 8; ++j) {
      Tl[r][cb + j] = f2bf(__expf(bf2f(v0[j]) - m) * inv);
      Tl[r][cb + 8 + j] = f2bf(__expf(bf2f(v1[j]) - m) * inv);
    }
    __syncthreads();
    const int c = tid >> 2, nb = (tid & 3) * 16;
    u16x8 o0, o1;
#pragma unroll
    for (int e = 0; e < 8; ++e) { o0[e] = Tl[nb + e][c]; o1[e] = Tl[nb + 8 + e][c]; }
    u16x8* op = (u16x8*)(KT + ((size_t)b * D_ + ct * 64 + c) * N_ + n0 + nb);
    op[0] = o0; op[1] = o1;
    __syncthreads();
  }
}

// ---------------- query: softmax over n (cols), write transposed QT[b,d,n] ----------------
__global__ __launch_bounds__(256) void query_sm_t(const u16* __restrict__ Qp,
                                                  u16* __restrict__ QT) {
  const int b = blockIdx.y, d0 = blockIdx.x * 64;
  const int tid = threadIdx.x, l = tid & 63, g = tid >> 6;
  __shared__ float pm[4][64], ps[4][64];
  __shared__ float cmax[64], cinv[64];
  __shared__ u16 Tl[64][72];
  const u16* base = Qp + (size_t)b * N_ * D_;
  float m = -1e30f, s = 0.f;
  for (int n = g * 256; n < g * 256 + 256; ++n) {
    const float x = bf2f(base[(size_t)n * D_ + d0 + l]);
    const float nm = fmaxf(m, x);
    s = s * __expf(m - nm) + __expf(x - nm);
    m = nm;
  }
  pm[g][l] = m; ps[g][l] = s;
  __syncthreads();
  if (tid < 64) {
    float M = pm[0][tid];
    for (int k2 = 1; k2 < 4; ++k2) M = fmaxf(M, pm[k2][tid]);
    float S = 0.f;
    for (int k2 = 0; k2 < 4; ++k2) S += ps[k2][tid] * __expf(pm[k2][tid] - M);
    cmax[tid] = M; cinv[tid] = 1.f / S;
  }
  __syncthreads();
  for (int nt = 0; nt < 16; ++nt) {
    const int r = tid >> 2, cb = (tid & 3) * 16;
    const u16x8* rp = (const u16x8*)(base + (size_t)(nt * 64 + r) * D_ + d0 + cb);
    u16x8 v0 = rp[0], v1 = rp[1];
#pragma unroll
    for (int j = 0; j < 8; ++j) {
      Tl[r][cb + j] = f2bf(__expf(bf2f(v0[j]) - cmax[cb + j]) * cinv[cb + j]);
      Tl[r][cb + 8 + j] =
          f2bf(__expf(bf2f(v1[j]) - cmax[cb + 8 + j]) * cinv[cb + 8 + j]);
    }
    __syncthreads();
    const int c = tid >> 2, nb = (tid & 3) * 16;
    u16x8 o0, o1;
#pragma unroll
    for (int e = 0; e < 8; ++e) { o0[e] = Tl[nb + e][c]; o1[e] = Tl[nb + 8 + e][c]; }
    u16x8* op = (u16x8*)(QT + ((size_t)b * D_ + d0 + c) * N_ + nt * 64 + nb);
    op[0] = o0; op[1] = o1;
    __syncthreads();
  }
}

extern "C" void kernel_launch(void* const* d_in, const int* in_sizes, int n_in,
                              void* d_out, int out_size, void* d_ws, size_t ws_size,
                              hipStream_t stream) {
  const float* x = (const float*)d_in[0];
  const float* Wk = (const float*)d_in[1];
  const float* Wq = (const float*)d_in[2];
  const float* Wv = (const float*)d_in[3];
  const float* Wr = (const float*)d_in[4];
  float* out = (float*)d_out;
  char* ws = (char*)d_ws;
  const size_t MB = 1ull << 20;

  u16* Xb  = (u16*)(ws + 0 * MB);
  u16* KT  = (u16*)(ws + 0 * MB);
  u16* Wkb = (u16*)(ws + 32 * MB);
  u16* Wqb = (u16*)(ws + 34 * MB);
  u16* Wvb = (u16*)(ws + 36 * MB);
  u16* Wrb = (u16*)(ws + 38 * MB);
  u16* Kp  = (u16*)(ws + 40 * MB);
  u16* St  = (u16*)(ws + 40 * MB);
  u16* Qp  = (u16*)(ws + 72 * MB);
  u16* Att = (u16*)(ws + 72 * MB);
  u16* V   = (u16*)(ws + 104 * MB);
  u16* QT  = (u16*)(ws + 136 * MB);

  const int nX = B_ * N_ * D_;
  cast_kernel<<<2048, 256, 0, stream>>>(x, Xb, nX / 4);
  cast4_kernel<<<1024, 256, 0, stream>>>(Wk, Wq, Wv, Wr, Wkb);

  // projections: (16384 x 1024) = Xb @ W^T   -> 64x4 tiles = 256 blocks
  gemm_bt256<u16><<<256, 512, 0, stream>>>(Xb, Wkb, Kp, D_, D_, 0, 0, 0, 4, 256);
  gemm_bt256<u16><<<256, 512, 0, stream>>>(Xb, Wqb, Qp, D_, D_, 0, 0, 0, 4, 256);
  gemm_bt256<u16><<<256, 512, 0, stream>>>(Xb, Wvb, V, D_, D_, 0, 0, 0, 4, 256);

  key_sm_t<<<dim3(N_ / 64, B_), 256, 0, stream>>>(Kp, KT);
  query_sm_t<<<dim3(D_ / 64, B_), 256, 0, stream>>>(Qp, QT);

  const long long sNN = (long long)N_ * D_;
  // St[b,d',d] = sum_n QT[b,d',n]*KT[b,d,n]: 16 batches x (4x4) = 256 blocks
  gemm_bt256<u16><<<256, 512, 0, stream>>>(QT, KT, St, N_, D_, sNN, sNN, sNN, 4, 16);
  // Att[b,m,d'] = sum_d V[b,m,d]*St[b,d',d]
  gemm_bt256<u16><<<256, 512, 0, stream>>>(V, St, Att, D_, D_, sNN, sNN, sNN, 4, 16);
  // out = Att @ Wr^T (fp32 epilogue)
  gemm_bt256<float><<<256, 512, 0, stream>>>(Att, Wrb, out, D_, D_, 0, 0, 0, 4, 256);
}